// Round 2
// baseline (11490.125 us; speedup 1.0000x reference)
//
#include <hip/hip_runtime.h>
#include <cstdint>
#include <cstddef>

// Problem constants (fixed by the reference).
#define B_   2048
#define T_   100
#define U_   512
#define NG_  2048   // 4*U
#define C_   10

typedef __attribute__((ext_vector_type(8))) short   short8;
typedef __attribute__((ext_vector_type(4))) float   floatx4;
typedef unsigned short ushort_t;

__device__ inline ushort_t f2bf(float f){
  unsigned u = __float_as_uint(f);
  unsigned r = (u + 0x7FFFu + ((u >> 16) & 1u)) >> 16;   // RNE
  return (ushort_t)r;
}
__device__ inline float bf2f(ushort_t b){ return __uint_as_float(((unsigned)b) << 16); }

__device__ inline float sigm(float x){ return 1.0f / (1.0f + __expf(-x)); }
__device__ inline float tanh_fast(float x){
  float a = fabsf(x);
  float e = __expf(-2.0f * a);          // no overflow: e in (0,1]
  float r = (1.0f - e) / (1.0f + e);
  return copysignf(r, x);
}

// Column permutation: permuted col p -> original gate-major col.
// Tile T (128 cols) owns u in [T*32, T*32+32); within tile: two 64-col halves
// (one per wave_n), each half = 4 gates x 16 u's, gate-major in 16-col groups.
__device__ inline int orig_col(int p){
  int Tt  = p >> 7;
  int loc = p & 127;
  int half = loc >> 6;
  int loc2 = loc & 63;
  int gate = loc2 >> 4;
  int uu   = (half << 4) | (loc2 & 15);
  return gate * U_ + Tt * 32 + uu;
}

#define AS1(p) ((const __attribute__((address_space(1))) void*)(p))
#define AS3(p) ((__attribute__((address_space(3))) void*)(p))

// ---------------------------------------------------------------------------
// One-time (per launch) weight repack: fp32 -> bf16, B^T (n-major) layout with
// gate-interleaved column permutation. Also permuted biases (fp32) and W0 row.
// ---------------------------------------------------------------------------
__global__ void convert_weights(
    const float* __restrict__ W0, const float* __restrict__ U0, const float* __restrict__ b0,
    const float* __restrict__ W1, const float* __restrict__ U1, const float* __restrict__ b1,
    const float* __restrict__ W2, const float* __restrict__ U2, const float* __restrict__ b2,
    ushort_t* __restrict__ Bt0, ushort_t* __restrict__ Bt1, ushort_t* __restrict__ Bt2,
    float* __restrict__ W0p, float* __restrict__ biasp)
{
  const int N0 = NG_ * 512;     // Bt0 elements
  const int N1 = NG_ * 1024;    // Bt1/Bt2 elements
  const int total = N0 + 2 * N1 + NG_ + 3 * NG_;
  int idx = blockIdx.x * 256 + threadIdx.x;
  if (idx >= total) return;

  if (idx < N0){
    int p = idx >> 9, k = idx & 511;
    Bt0[idx] = f2bf(U0[(size_t)k * NG_ + orig_col(p)]);
  } else if (idx < N0 + N1){
    int j = idx - N0; int p = j >> 10, k = j & 1023;
    int oc = orig_col(p);
    float v = (k < 512) ? W1[(size_t)k * NG_ + oc] : U1[(size_t)(k - 512) * NG_ + oc];
    Bt1[j] = f2bf(v);
  } else if (idx < N0 + 2 * N1){
    int j = idx - N0 - N1; int p = j >> 10, k = j & 1023;
    int oc = orig_col(p);
    float v = (k < 512) ? W2[(size_t)k * NG_ + oc] : U2[(size_t)(k - 512) * NG_ + oc];
    Bt2[j] = f2bf(v);
  } else if (idx < N0 + 2 * N1 + NG_){
    int p = idx - N0 - 2 * N1;
    W0p[p] = W0[orig_col(p)];
  } else {
    int j = idx - N0 - 2 * N1 - NG_;
    int l = j >> 11, p = j & 2047;
    const float* bs = (l == 0) ? b0 : (l == 1) ? b1 : b2;
    biasp[j] = bs[orig_col(p)];
  }
}

// ---------------------------------------------------------------------------
// One fused GEMM (bf16 MFMA) + LSTM-cell task for a (layer, timestep),
// 128x128 tile at (mt, nt). Same structure as round-1 lstm_step, now a
// device function called from the persistent kernel.
// ---------------------------------------------------------------------------
template<int LAYER>
__device__ __forceinline__ void do_task(
    const ushort_t* __restrict__ A0,   // phase-0 A (h_below / h_prev for L0)
    const ushort_t* __restrict__ A1,   // phase-1 A (h_prev), LAYER>0
    const ushort_t* __restrict__ Bt,   // (2048 x K) bf16, n-major permuted
    const float* __restrict__ biasp,   // permuted bias for this layer (2048)
    const float* __restrict__ W0p,     // permuted W0 row (L0 only)
    const float* __restrict__ x,       // (B,T) fp32 (L0 only)
    const int* __restrict__ mask,      // (B,T) int32
    float* __restrict__ cbuf,          // (B,U) fp32, in/out
    const ushort_t* __restrict__ hprev,// this layer's previous h (mask carry)
    ushort_t* __restrict__ hout,       // (B,U) bf16 out
    int t, int mt, int nt,
    ushort_t* tA, ushort_t* tB)
{
  constexpr int NPHASE = (LAYER == 0) ? 1 : 2;
  constexpr bool IS_L0 = (LAYER == 0);
  constexpr int K = NPHASE * 512;

  const int tid  = threadIdx.x;
  const int wv   = tid >> 6;
  const int lane = tid & 63;
  const int qd   = lane >> 4;     // quad 0..3
  const int l16  = lane & 15;
  const int wave_m = wv >> 1;     // 0..1
  const int wave_n = wv & 1;      // 0..1
  const int m0 = mt * 128, n0 = nt * 128;

  floatx4 acc[4][4];
  #pragma unroll
  for (int i = 0; i < 4; ++i)
    #pragma unroll
    for (int j = 0; j < 4; ++j) acc[i][j] = (floatx4){0.f, 0.f, 0.f, 0.f};

  #pragma unroll
  for (int ph = 0; ph < NPHASE; ++ph){
    const ushort_t* A = (NPHASE == 2 && ph == 1) ? A1 : A0;
    for (int k0 = 0; k0 < 512; k0 += 32){
      // Stage A-tile (128x32) and B-tile (128x32) via direct-to-LDS 16B loads.
      #pragma unroll
      for (int cc2 = 0; cc2 < 2; ++cc2){
        int i  = cc2 * 256 + wv * 64 + lane;
        int r  = i >> 2, cc = i & 3;
        const ushort_t* ga = A + (size_t)(m0 + r) * U_ + k0 + cc * 8;
        __builtin_amdgcn_global_load_lds(AS1(ga), AS3(&tA[(cc2 * 256 + wv * 64) * 8]), 16, 0, 0);
        const ushort_t* gb = Bt + (size_t)(n0 + r) * K + ph * 512 + k0 + cc * 8;
        __builtin_amdgcn_global_load_lds(AS1(gb), AS3(&tB[(cc2 * 256 + wv * 64) * 8]), 16, 0, 0);
      }
      __syncthreads();

      short8 af[4], bfr[4];
      #pragma unroll
      for (int wm = 0; wm < 4; ++wm)
        af[wm] = *(const short8*)&tA[(wave_m * 64 + wm * 16 + l16) * 32 + qd * 8];
      #pragma unroll
      for (int wn = 0; wn < 4; ++wn)
        bfr[wn] = *(const short8*)&tB[(wave_n * 64 + wn * 16 + l16) * 32 + qd * 8];
      #pragma unroll
      for (int wm = 0; wm < 4; ++wm)
        #pragma unroll
        for (int wn = 0; wn < 4; ++wn)
          acc[wm][wn] = __builtin_amdgcn_mfma_f32_16x16x32_bf16(af[wm], bfr[wn], acc[wm][wn], 0, 0, 0);
      __syncthreads();
    }
  }

  // ---- epilogue: LSTM cell, fully in-register per lane ----
  const int u  = nt * 32 + wave_n * 16 + l16;
  const int pb = nt * 128 + wave_n * 64 + l16;
  const float bi = biasp[pb], bf_ = biasp[pb + 16], bg = biasp[pb + 32], bo = biasp[pb + 48];
  float wi = 0.f, wf = 0.f, wg = 0.f, wo = 0.f;
  if (IS_L0){ wi = W0p[pb]; wf = W0p[pb + 16]; wg = W0p[pb + 32]; wo = W0p[pb + 48]; }

  #pragma unroll
  for (int wm = 0; wm < 4; ++wm){
    #pragma unroll
    for (int reg = 0; reg < 4; ++reg){
      int b = m0 + wave_m * 64 + wm * 16 + qd * 4 + reg;
      float zi = acc[wm][0][reg] + bi;
      float zf = acc[wm][1][reg] + bf_;
      float zg = acc[wm][2][reg] + bg;
      float zo = acc[wm][3][reg] + bo;
      if (IS_L0){
        float xv = x[(size_t)b * T_ + t];
        zi += xv * wi; zf += xv * wf; zg += xv * wg; zo += xv * wo;
      }
      int mk = mask[(size_t)b * T_ + t];
      size_t su = (size_t)b * U_ + u;
      float c_old = cbuf[su];
      float i_ = sigm(zi), f_ = sigm(zf), g_ = tanh_fast(zg), o_ = sigm(zo);
      float c_new = f_ * c_old + i_ * g_;
      float h_new = o_ * tanh_fast(c_new);
      ushort_t hb = mk ? f2bf(h_new) : hprev[su];
      cbuf[su] = mk ? c_new : c_old;
      hout[su] = hb;
    }
  }
}

// ---------------------------------------------------------------------------
// Persistent wavefront kernel: 102 phases; phase s does L0(t=s), L1(t=s-1),
// L2(t=s-2) — mutually independent — then one device-scope grid barrier.
// grid = 256 blocks (1/CU, co-resident). Block keeps a fixed (mt,nt) so its
// weight slices stay hot in its XCD's L2 across all timesteps.
// ---------------------------------------------------------------------------
__global__ __launch_bounds__(256) void lstm_persistent(
    const ushort_t* __restrict__ Bt0, const ushort_t* __restrict__ Bt1,
    const ushort_t* __restrict__ Bt2, const float* __restrict__ biasp,
    const float* __restrict__ W0p, const float* __restrict__ x,
    const int* __restrict__ mask,
    ushort_t* h00, ushort_t* h01, ushort_t* h10, ushort_t* h11,
    ushort_t* h20, ushort_t* h21,
    float* c0, float* c1, float* c2,
    unsigned* bar)
{
  __shared__ __align__(16) ushort_t tA[128 * 32];
  __shared__ __align__(16) ushort_t tB[128 * 32];

  // Swizzled tile identity: assuming XCD = blockIdx%8, each XCD covers
  // 4 mt x 8 nt -> small per-XCD A working set, B slices L2-resident.
  const int bidx = blockIdx.x;
  const int xc = bidx & 7, g = bidx >> 3;
  const int mt = ((xc >> 1) << 2) | (g >> 3);   // 0..15
  const int nt = ((xc & 1) << 3) | (g & 7);     // 0..15

  ushort_t* h0[2] = {h00, h01};
  ushort_t* h1[2] = {h10, h11};
  ushort_t* h2[2] = {h20, h21};

  unsigned target = 0;
  for (int s = 0; s < 102; ++s){
    if (s < 100){
      int t = s, p = t & 1;
      do_task<0>(h0[p], nullptr, Bt0, biasp, W0p, x, mask,
                 c0, h0[p], h0[p ^ 1], t, mt, nt, tA, tB);
    }
    if (s >= 1 && s <= 100){
      int t = s - 1, p = t & 1;
      do_task<1>(h0[p ^ 1], h1[p], Bt1, biasp + NG_, nullptr, x, mask,
                 c1, h1[p], h1[p ^ 1], t, mt, nt, tA, tB);
    }
    if (s >= 2){
      int t = s - 2, p = t & 1;
      do_task<2>(h1[p ^ 1], h2[p], Bt2, biasp + 2 * NG_, nullptr, x, mask,
                 c2, h2[p], h2[p ^ 1], t, mt, nt, tA, tB);
    }
    // ---- grid barrier (device-scope; cross-XCD safe) ----
    target += 256;
    __syncthreads();
    if (threadIdx.x == 0){
      __threadfence();                 // release: write back this XCD's L2
      atomicAdd(bar, 1u);              // device-scope by default on CDNA
      while (__hip_atomic_load(bar, __ATOMIC_RELAXED, __HIP_MEMORY_SCOPE_AGENT) < target)
        __builtin_amdgcn_s_sleep(4);
      __threadfence();                 // acquire: invalidate stale L1/L2
    }
    __syncthreads();
  }
}

// ---------------------------------------------------------------------------
// Head: logits = h2 @ Wd + bd, softmax. One wave per batch row.
// ---------------------------------------------------------------------------
__global__ __launch_bounds__(256) void head_softmax(
    const ushort_t* __restrict__ h2, const float* __restrict__ Wd,
    const float* __restrict__ bd, float* __restrict__ out)
{
  int wv = threadIdx.x >> 6, lane = threadIdx.x & 63;
  int row = blockIdx.x * 4 + wv;
  const ushort_t* hr = h2 + (size_t)row * U_;

  float acc[C_];
  #pragma unroll
  for (int c = 0; c < C_; ++c) acc[c] = 0.f;

  short8 hv = *(const short8*)&hr[lane * 8];
  #pragma unroll
  for (int j = 0; j < 8; ++j){
    float hf = bf2f((ushort_t)hv[j]);
    int k = lane * 8 + j;
    #pragma unroll
    for (int c = 0; c < C_; ++c) acc[c] += hf * Wd[k * C_ + c];
  }
  #pragma unroll
  for (int c = 0; c < C_; ++c){
    float v = acc[c];
    #pragma unroll
    for (int off = 32; off > 0; off >>= 1) v += __shfl_xor(v, off);
    acc[c] = v + bd[c];
  }
  float mx = acc[0];
  #pragma unroll
  for (int c = 1; c < C_; ++c) mx = fmaxf(mx, acc[c]);
  float e[C_]; float s = 0.f;
  #pragma unroll
  for (int c = 0; c < C_; ++c){ e[c] = __expf(acc[c] - mx); s += e[c]; }
  float inv = 1.0f / s;
  if (lane == 0){
    #pragma unroll
    for (int c = 0; c < C_; ++c) out[(size_t)row * C_ + c] = e[c] * inv;
  }
}

// ---------------------------------------------------------------------------
extern "C" void kernel_launch(void* const* d_in, const int* in_sizes, int n_in,
                              void* d_out, int out_size, void* d_ws, size_t ws_size,
                              hipStream_t stream)
{
  const float* x  = (const float*)d_in[0];
  const int*  mask= (const int*)  d_in[1];
  const float* W0 = (const float*)d_in[2];
  const float* U0 = (const float*)d_in[3];
  const float* b0 = (const float*)d_in[4];
  const float* W1 = (const float*)d_in[5];
  const float* U1 = (const float*)d_in[6];
  const float* b1 = (const float*)d_in[7];
  const float* W2 = (const float*)d_in[8];
  const float* U2 = (const float*)d_in[9];
  const float* b2 = (const float*)d_in[10];
  const float* Wd = (const float*)d_in[11];
  const float* bd = (const float*)d_in[12];
  float* out = (float*)d_out;

  char* ws = (char*)d_ws;
  size_t off = 0;
  auto alloc = [&](size_t sz) -> char* {
    char* p = ws + off; off = (off + sz + 255) & ~(size_t)255; return p;
  };
  ushort_t* Bt0  = (ushort_t*)alloc((size_t)NG_ * 512 * 2);
  ushort_t* Bt1  = (ushort_t*)alloc((size_t)NG_ * 1024 * 2);
  ushort_t* Bt2  = (ushort_t*)alloc((size_t)NG_ * 1024 * 2);
  float*    W0p  = (float*)alloc((size_t)NG_ * 4);
  float*    biasp= (float*)alloc((size_t)3 * NG_ * 4);

  // State: h[3][2] (bf16) + c[3] (fp32) + barrier counter, one memset region.
  const size_t hsz = (size_t)B_ * U_ * 2;
  const size_t csz = (size_t)B_ * U_ * 4;
  char* state = alloc(6 * hsz + 3 * csz + 256);
  ushort_t* hb[3][2]; float* cb[3];
  {
    char* pp = state;
    for (int l = 0; l < 3; ++l)
      for (int par = 0; par < 2; ++par){ hb[l][par] = (ushort_t*)pp; pp += hsz; }
    for (int l = 0; l < 3; ++l){ cb[l] = (float*)pp; pp += csz; }
  }
  unsigned* bar = (unsigned*)(state + 6 * hsz + 3 * csz);

  hipMemsetAsync(state, 0, 6 * hsz + 3 * csz + 256, stream);

  const int total = NG_ * 512 + 2 * NG_ * 1024 + NG_ + 3 * NG_;
  convert_weights<<<(total + 255) / 256, 256, 0, stream>>>(
      W0, U0, b0, W1, U1, b1, W2, U2, b2, Bt0, Bt1, Bt2, W0p, biasp);

  lstm_persistent<<<256, 256, 0, stream>>>(
      Bt0, Bt1, Bt2, biasp, W0p, x, mask,
      hb[0][0], hb[0][1], hb[1][0], hb[1][1], hb[2][0], hb[2][1],
      cb[0], cb[1], cb[2], bar);

  // T=100: layer-2 final h (t=99) lands in parity-0 buffer.
  head_softmax<<<B_ / 4, 256, 0, stream>>>(hb[2][0], Wd, bd, out);
}

// Round 3
// 3957.126 us; speedup vs baseline: 2.9037x; 2.9037x over previous
//
#include <hip/hip_runtime.h>
#include <cstdint>
#include <cstddef>

// Problem constants (fixed by the reference).
#define B_   2048
#define T_   100
#define U_   512
#define NG_  2048   // 4*U
#define C_   10

typedef __attribute__((ext_vector_type(8))) short   short8;
typedef __attribute__((ext_vector_type(4))) float   floatx4;
typedef unsigned short ushort_t;

__device__ inline ushort_t f2bf(float f){
  unsigned u = __float_as_uint(f);
  unsigned r = (u + 0x7FFFu + ((u >> 16) & 1u)) >> 16;   // RNE
  return (ushort_t)r;
}
__device__ inline float bf2f(ushort_t b){ return __uint_as_float(((unsigned)b) << 16); }

__device__ inline float sigm(float x){ return 1.0f / (1.0f + __expf(-x)); }
__device__ inline float tanh_fast(float x){
  float a = fabsf(x);
  float e = __expf(-2.0f * a);          // no overflow: e in (0,1]
  float r = (1.0f - e) / (1.0f + e);
  return copysignf(r, x);
}

// Column permutation: permuted col p -> original gate-major col.
// Tile T (128 cols) owns u in [T*32, T*32+32); within tile: two 64-col halves
// (one per wave_n), each half = 4 gates x 16 u's, gate-major in 16-col groups.
__device__ inline int orig_col(int p){
  int Tt  = p >> 7;
  int loc = p & 127;
  int half = loc >> 6;
  int loc2 = loc & 63;
  int gate = loc2 >> 4;
  int uu   = (half << 4) | (loc2 & 15);
  return gate * U_ + Tt * 32 + uu;
}

#define AS1(p) ((const __attribute__((address_space(1))) void*)(p))
#define AS3(p) ((__attribute__((address_space(3))) void*)(p))

// ---------------------------------------------------------------------------
// One-time (per launch) weight repack: fp32 -> bf16, B^T (n-major) layout with
// gate-interleaved column permutation. Also permuted biases (fp32) and W0 row.
// ---------------------------------------------------------------------------
__global__ void convert_weights(
    const float* __restrict__ W0, const float* __restrict__ U0, const float* __restrict__ b0,
    const float* __restrict__ W1, const float* __restrict__ U1, const float* __restrict__ b1,
    const float* __restrict__ W2, const float* __restrict__ U2, const float* __restrict__ b2,
    ushort_t* __restrict__ Bt0, ushort_t* __restrict__ Bt1, ushort_t* __restrict__ Bt2,
    float* __restrict__ W0p, float* __restrict__ biasp)
{
  const int N0 = NG_ * 512;     // Bt0 elements
  const int N1 = NG_ * 1024;    // Bt1/Bt2 elements
  const int total = N0 + 2 * N1 + NG_ + 3 * NG_;
  int idx = blockIdx.x * 256 + threadIdx.x;
  if (idx >= total) return;

  if (idx < N0){
    int p = idx >> 9, k = idx & 511;
    Bt0[idx] = f2bf(U0[(size_t)k * NG_ + orig_col(p)]);
  } else if (idx < N0 + N1){
    int j = idx - N0; int p = j >> 10, k = j & 1023;
    int oc = orig_col(p);
    float v = (k < 512) ? W1[(size_t)k * NG_ + oc] : U1[(size_t)(k - 512) * NG_ + oc];
    Bt1[j] = f2bf(v);
  } else if (idx < N0 + 2 * N1){
    int j = idx - N0 - N1; int p = j >> 10, k = j & 1023;
    int oc = orig_col(p);
    float v = (k < 512) ? W2[(size_t)k * NG_ + oc] : U2[(size_t)(k - 512) * NG_ + oc];
    Bt2[j] = f2bf(v);
  } else if (idx < N0 + 2 * N1 + NG_){
    int p = idx - N0 - 2 * N1;
    W0p[p] = W0[orig_col(p)];
  } else {
    int j = idx - N0 - 2 * N1 - NG_;
    int l = j >> 11, p = j & 2047;
    const float* bs = (l == 0) ? b0 : (l == 1) ? b1 : b2;
    biasp[j] = bs[orig_col(p)];
  }
}

// ---------------------------------------------------------------------------
// One fused GEMM (bf16 MFMA) + LSTM-cell task for a (layer, timestep),
// 128x128 tile at (mt, nt).
//   z[b, p] = sum_k A[b,k] * Bt[p,k]   (A = h_below | h_prev, bf16)
// 256 threads = 2x2 waves, each wave 4x4 frags of 16x16x32.
// Epilogue: per-lane gate quad (i,f,g,o) -> cell -> masked h (bf16) + c (fp32).
// ---------------------------------------------------------------------------
template<int LAYER>
__device__ __forceinline__ void do_task(
    const ushort_t* __restrict__ A0,   // phase-0 A (h_below / h_prev for L0)
    const ushort_t* __restrict__ A1,   // phase-1 A (h_prev), LAYER>0
    const ushort_t* __restrict__ Bt,   // (2048 x K) bf16, n-major permuted
    const float* __restrict__ biasp,   // permuted bias for this layer (2048)
    const float* __restrict__ W0p,     // permuted W0 row (L0 only)
    const float* __restrict__ x,       // (B,T) fp32 (L0 only)
    const int* __restrict__ mask,      // (B,T) int32
    float* __restrict__ cbuf,          // (B,U) fp32, in/out
    const ushort_t* __restrict__ hprev,// this layer's previous h (mask carry)
    ushort_t* __restrict__ hout,       // (B,U) bf16 out
    int t, int mt, int nt,
    ushort_t* tA, ushort_t* tB)
{
  constexpr int NPHASE = (LAYER == 0) ? 1 : 2;
  constexpr bool IS_L0 = (LAYER == 0);
  constexpr int K = NPHASE * 512;

  const int tid  = threadIdx.x;
  const int wv   = tid >> 6;
  const int lane = tid & 63;
  const int qd   = lane >> 4;     // quad 0..3
  const int l16  = lane & 15;
  const int wave_m = wv >> 1;     // 0..1
  const int wave_n = wv & 1;      // 0..1
  const int m0 = mt * 128, n0 = nt * 128;

  floatx4 acc[4][4];
  #pragma unroll
  for (int i = 0; i < 4; ++i)
    #pragma unroll
    for (int j = 0; j < 4; ++j) acc[i][j] = (floatx4){0.f, 0.f, 0.f, 0.f};

  #pragma unroll
  for (int ph = 0; ph < NPHASE; ++ph){
    const ushort_t* A = (NPHASE == 2 && ph == 1) ? A1 : A0;
    for (int k0 = 0; k0 < 512; k0 += 32){
      // Stage A-tile (128x32) and B-tile (128x32) via direct-to-LDS 16B loads.
      #pragma unroll
      for (int cc2 = 0; cc2 < 2; ++cc2){
        int i  = cc2 * 256 + wv * 64 + lane;
        int r  = i >> 2, cc = i & 3;
        const ushort_t* ga = A + (size_t)(m0 + r) * U_ + k0 + cc * 8;
        __builtin_amdgcn_global_load_lds(AS1(ga), AS3(&tA[(cc2 * 256 + wv * 64) * 8]), 16, 0, 0);
        const ushort_t* gb = Bt + (size_t)(n0 + r) * K + ph * 512 + k0 + cc * 8;
        __builtin_amdgcn_global_load_lds(AS1(gb), AS3(&tB[(cc2 * 256 + wv * 64) * 8]), 16, 0, 0);
      }
      __syncthreads();

      short8 af[4], bfr[4];
      #pragma unroll
      for (int wm = 0; wm < 4; ++wm)
        af[wm] = *(const short8*)&tA[(wave_m * 64 + wm * 16 + l16) * 32 + qd * 8];
      #pragma unroll
      for (int wn = 0; wn < 4; ++wn)
        bfr[wn] = *(const short8*)&tB[(wave_n * 64 + wn * 16 + l16) * 32 + qd * 8];
      #pragma unroll
      for (int wm = 0; wm < 4; ++wm)
        #pragma unroll
        for (int wn = 0; wn < 4; ++wn)
          acc[wm][wn] = __builtin_amdgcn_mfma_f32_16x16x32_bf16(af[wm], bfr[wn], acc[wm][wn], 0, 0, 0);
      __syncthreads();
    }
  }

  // ---- epilogue: LSTM cell, fully in-register per lane ----
  const int u  = nt * 32 + wave_n * 16 + l16;
  const int pb = nt * 128 + wave_n * 64 + l16;
  const float bi = biasp[pb], bf_ = biasp[pb + 16], bg = biasp[pb + 32], bo = biasp[pb + 48];
  float wi = 0.f, wf = 0.f, wg = 0.f, wo = 0.f;
  if (IS_L0){ wi = W0p[pb]; wf = W0p[pb + 16]; wg = W0p[pb + 32]; wo = W0p[pb + 48]; }

  #pragma unroll
  for (int wm = 0; wm < 4; ++wm){
    #pragma unroll
    for (int reg = 0; reg < 4; ++reg){
      int b = m0 + wave_m * 64 + wm * 16 + qd * 4 + reg;
      float zi = acc[wm][0][reg] + bi;
      float zf = acc[wm][1][reg] + bf_;
      float zg = acc[wm][2][reg] + bg;
      float zo = acc[wm][3][reg] + bo;
      if (IS_L0){
        float xv = x[(size_t)b * T_ + t];
        zi += xv * wi; zf += xv * wf; zg += xv * wg; zo += xv * wo;
      }
      int mk = mask[(size_t)b * T_ + t];
      size_t su = (size_t)b * U_ + u;
      float c_old = cbuf[su];
      float i_ = sigm(zi), f_ = sigm(zf), g_ = tanh_fast(zg), o_ = sigm(zo);
      float c_new = f_ * c_old + i_ * g_;
      float h_new = o_ * tanh_fast(c_new);
      ushort_t hb = mk ? f2bf(h_new) : hprev[su];
      cbuf[su] = mk ? c_new : c_old;
      hout[su] = hb;
    }
  }
}

// ---------------------------------------------------------------------------
// One wavefront phase: L0(t=s), L1(t=s-1), L2(t=s-2) are independent ->
// 768 blocks (3 tasks x 256 tiles) = 3 blocks/CU so staging latency of one
// block overlaps MFMA of another (m114). Stream order between phases gives
// coherence for free; no fences, weights stay hot in L2.
// ---------------------------------------------------------------------------
__global__ __launch_bounds__(256, 3) void lstm_phase(
    const ushort_t* __restrict__ Bt0, const ushort_t* __restrict__ Bt1,
    const ushort_t* __restrict__ Bt2, const float* __restrict__ biasp,
    const float* __restrict__ W0p, const float* __restrict__ x,
    const int* __restrict__ mask,
    ushort_t* h00, ushort_t* h01, ushort_t* h10, ushort_t* h11,
    ushort_t* h20, ushort_t* h21,
    float* c0, float* c1, float* c2,
    int s)
{
  __shared__ __align__(16) ushort_t tA[128 * 32];
  __shared__ __align__(16) ushort_t tB[128 * 32];

  const int lin  = blockIdx.x;
  const int task = lin % 3;         // interleave tasks across adjacent blocks
  const int tile = lin / 3;         // 0..255
  const int mt = tile >> 4, nt = tile & 15;

  ushort_t* h0[2] = {h00, h01};
  ushort_t* h1[2] = {h10, h11};
  ushort_t* h2[2] = {h20, h21};

  if (task == 0){
    if (s >= 100) return;
    int t = s, p = t & 1;
    do_task<0>(h0[p], nullptr, Bt0, biasp, W0p, x, mask,
               c0, h0[p], h0[p ^ 1], t, mt, nt, tA, tB);
  } else if (task == 1){
    if (s < 1 || s > 100) return;
    int t = s - 1, p = t & 1;
    do_task<1>(h0[p ^ 1], h1[p], Bt1, biasp + NG_, nullptr, x, mask,
               c1, h1[p], h1[p ^ 1], t, mt, nt, tA, tB);
  } else {
    if (s < 2) return;
    int t = s - 2, p = t & 1;
    do_task<2>(h1[p ^ 1], h2[p], Bt2, biasp + 2 * NG_, nullptr, x, mask,
               c2, h2[p], h2[p ^ 1], t, mt, nt, tA, tB);
  }
}

// ---------------------------------------------------------------------------
// Head: logits = h2 @ Wd + bd, softmax. One wave per batch row.
// ---------------------------------------------------------------------------
__global__ __launch_bounds__(256) void head_softmax(
    const ushort_t* __restrict__ h2, const float* __restrict__ Wd,
    const float* __restrict__ bd, float* __restrict__ out)
{
  int wv = threadIdx.x >> 6, lane = threadIdx.x & 63;
  int row = blockIdx.x * 4 + wv;
  const ushort_t* hr = h2 + (size_t)row * U_;

  float acc[C_];
  #pragma unroll
  for (int c = 0; c < C_; ++c) acc[c] = 0.f;

  short8 hv = *(const short8*)&hr[lane * 8];
  #pragma unroll
  for (int j = 0; j < 8; ++j){
    float hf = bf2f((ushort_t)hv[j]);
    int k = lane * 8 + j;
    #pragma unroll
    for (int c = 0; c < C_; ++c) acc[c] += hf * Wd[k * C_ + c];
  }
  #pragma unroll
  for (int c = 0; c < C_; ++c){
    float v = acc[c];
    #pragma unroll
    for (int off = 32; off > 0; off >>= 1) v += __shfl_xor(v, off);
    acc[c] = v + bd[c];
  }
  float mx = acc[0];
  #pragma unroll
  for (int c = 1; c < C_; ++c) mx = fmaxf(mx, acc[c]);
  float e[C_]; float s = 0.f;
  #pragma unroll
  for (int c = 0; c < C_; ++c){ e[c] = __expf(acc[c] - mx); s += e[c]; }
  float inv = 1.0f / s;
  if (lane == 0){
    #pragma unroll
    for (int c = 0; c < C_; ++c) out[(size_t)row * C_ + c] = e[c] * inv;
  }
}

// ---------------------------------------------------------------------------
extern "C" void kernel_launch(void* const* d_in, const int* in_sizes, int n_in,
                              void* d_out, int out_size, void* d_ws, size_t ws_size,
                              hipStream_t stream)
{
  const float* x  = (const float*)d_in[0];
  const int*  mask= (const int*)  d_in[1];
  const float* W0 = (const float*)d_in[2];
  const float* U0 = (const float*)d_in[3];
  const float* b0 = (const float*)d_in[4];
  const float* W1 = (const float*)d_in[5];
  const float* U1 = (const float*)d_in[6];
  const float* b1 = (const float*)d_in[7];
  const float* W2 = (const float*)d_in[8];
  const float* U2 = (const float*)d_in[9];
  const float* b2 = (const float*)d_in[10];
  const float* Wd = (const float*)d_in[11];
  const float* bd = (const float*)d_in[12];
  float* out = (float*)d_out;

  char* ws = (char*)d_ws;
  size_t off = 0;
  auto alloc = [&](size_t sz) -> char* {
    char* p = ws + off; off = (off + sz + 255) & ~(size_t)255; return p;
  };
  ushort_t* Bt0  = (ushort_t*)alloc((size_t)NG_ * 512 * 2);
  ushort_t* Bt1  = (ushort_t*)alloc((size_t)NG_ * 1024 * 2);
  ushort_t* Bt2  = (ushort_t*)alloc((size_t)NG_ * 1024 * 2);
  float*    W0p  = (float*)alloc((size_t)NG_ * 4);
  float*    biasp= (float*)alloc((size_t)3 * NG_ * 4);

  // State: h[3][2] (bf16) + c[3] (fp32), one contiguous memset region.
  const size_t hsz = (size_t)B_ * U_ * 2;
  const size_t csz = (size_t)B_ * U_ * 4;
  char* state = alloc(6 * hsz + 3 * csz);
  ushort_t* hb[3][2]; float* cb[3];
  {
    char* pp = state;
    for (int l = 0; l < 3; ++l)
      for (int par = 0; par < 2; ++par){ hb[l][par] = (ushort_t*)pp; pp += hsz; }
    for (int l = 0; l < 3; ++l){ cb[l] = (float*)pp; pp += csz; }
  }

  hipMemsetAsync(state, 0, 6 * hsz + 3 * csz, stream);

  const int total = NG_ * 512 + 2 * NG_ * 1024 + NG_ + 3 * NG_;
  convert_weights<<<(total + 255) / 256, 256, 0, stream>>>(
      W0, U0, b0, W1, U1, b1, W2, U2, b2, Bt0, Bt1, Bt2, W0p, biasp);

  for (int s = 0; s < 102; ++s){
    lstm_phase<<<768, 256, 0, stream>>>(
        Bt0, Bt1, Bt2, biasp, W0p, x, mask,
        hb[0][0], hb[0][1], hb[1][0], hb[1][1], hb[2][0], hb[2][1],
        cb[0], cb[1], cb[2], s);
  }

  // T=100: layer-2 final h (t=99) lands in parity-0 buffer.
  head_softmax<<<B_ / 4, 256, 0, stream>>>(hb[2][0], Wd, bd, out);
}

// Round 4
// 3480.342 us; speedup vs baseline: 3.3014x; 1.1370x over previous
//
#include <hip/hip_runtime.h>
#include <cstdint>
#include <cstddef>

// Problem constants (fixed by the reference).
#define B_   2048
#define T_   100
#define U_   512
#define NG_  2048   // 4*U
#define C_   10

typedef __attribute__((ext_vector_type(8))) short   short8;
typedef __attribute__((ext_vector_type(4))) float   floatx4;
typedef unsigned short ushort_t;

__device__ inline ushort_t f2bf(float f){
  unsigned u = __float_as_uint(f);
  unsigned r = (u + 0x7FFFu + ((u >> 16) & 1u)) >> 16;   // RNE
  return (ushort_t)r;
}
__device__ inline float bf2f(ushort_t b){ return __uint_as_float(((unsigned)b) << 16); }

__device__ inline float sigm(float x){ return 1.0f / (1.0f + __expf(-x)); }
__device__ inline float tanh_fast(float x){
  float a = fabsf(x);
  float e = __expf(-2.0f * a);          // no overflow: e in (0,1]
  float r = (1.0f - e) / (1.0f + e);
  return copysignf(r, x);
}

// Column permutation: permuted col p -> original gate-major col.
// Tile T (128 cols) owns u in [T*32, T*32+32); within tile: two 64-col halves
// (one per wave_n), each half = 4 gates x 16 u's, gate-major in 16-col groups.
__device__ inline int orig_col(int p){
  int Tt  = p >> 7;
  int loc = p & 127;
  int half = loc >> 6;
  int loc2 = loc & 63;
  int gate = loc2 >> 4;
  int uu   = (half << 4) | (loc2 & 15);
  return gate * U_ + Tt * 32 + uu;
}

#define AS1(p) ((const __attribute__((address_space(1))) void*)(p))
#define AS3(p) ((__attribute__((address_space(3))) void*)(p))

// ---------------------------------------------------------------------------
// One-time (per launch) weight repack: fp32 -> bf16, B^T (n-major) layout with
// gate-interleaved column permutation. Also permuted biases (fp32) and W0 row.
// ---------------------------------------------------------------------------
__global__ void convert_weights(
    const float* __restrict__ W0, const float* __restrict__ U0, const float* __restrict__ b0,
    const float* __restrict__ W1, const float* __restrict__ U1, const float* __restrict__ b1,
    const float* __restrict__ W2, const float* __restrict__ U2, const float* __restrict__ b2,
    ushort_t* __restrict__ Bt0, ushort_t* __restrict__ Bt1, ushort_t* __restrict__ Bt2,
    float* __restrict__ W0p, float* __restrict__ biasp)
{
  const int N0 = NG_ * 512;     // Bt0 elements
  const int N1 = NG_ * 1024;    // Bt1/Bt2 elements
  const int total = N0 + 2 * N1 + NG_ + 3 * NG_;
  int idx = blockIdx.x * 256 + threadIdx.x;
  if (idx >= total) return;

  if (idx < N0){
    int p = idx >> 9, k = idx & 511;
    Bt0[idx] = f2bf(U0[(size_t)k * NG_ + orig_col(p)]);
  } else if (idx < N0 + N1){
    int j = idx - N0; int p = j >> 10, k = j & 1023;
    int oc = orig_col(p);
    float v = (k < 512) ? W1[(size_t)k * NG_ + oc] : U1[(size_t)(k - 512) * NG_ + oc];
    Bt1[j] = f2bf(v);
  } else if (idx < N0 + 2 * N1){
    int j = idx - N0 - N1; int p = j >> 10, k = j & 1023;
    int oc = orig_col(p);
    float v = (k < 512) ? W2[(size_t)k * NG_ + oc] : U2[(size_t)(k - 512) * NG_ + oc];
    Bt2[j] = f2bf(v);
  } else if (idx < N0 + 2 * N1 + NG_){
    int p = idx - N0 - 2 * N1;
    W0p[p] = W0[orig_col(p)];
  } else {
    int j = idx - N0 - 2 * N1 - NG_;
    int l = j >> 11, p = j & 2047;
    const float* bs = (l == 0) ? b0 : (l == 1) ? b1 : b2;
    biasp[j] = bs[orig_col(p)];
  }
}

// ---------------------------------------------------------------------------
// One fused GEMM (bf16 MFMA) + LSTM-cell task for a (layer, timestep),
// 128x128 tile at (mt, nt). BK=64 K-loop: per iter stage 128x64 A and B
// tiles via global_load_lds(16B) with a bank-conflict-killing slot rotation
// (slot (r,j) holds global 16B-chunk (j+r)&7; readback j=(q-r)&7 spreads the
// 16-lane ds_read_b128 groups across 8 bank-quads -> 2-way = free).
// 256 threads = 2x2 waves, each wave 4x4 frags of 16x16x32, 2 k-steps/iter.
// ---------------------------------------------------------------------------
template<int LAYER>
__device__ __forceinline__ void do_task(
    const ushort_t* __restrict__ A0,   // phase-0 A (h_below / h_prev for L0)
    const ushort_t* __restrict__ A1,   // phase-1 A (h_prev), LAYER>0
    const ushort_t* __restrict__ Bt,   // (2048 x K) bf16, n-major permuted
    const float* __restrict__ biasp,   // permuted bias for this layer (2048)
    const float* __restrict__ W0p,     // permuted W0 row (L0 only)
    const float* __restrict__ x,       // (B,T) fp32 (L0 only)
    const int* __restrict__ mask,      // (B,T) int32
    float* __restrict__ cbuf,          // (B,U) fp32, in/out
    const ushort_t* __restrict__ hprev,// this layer's previous h (mask carry)
    ushort_t* __restrict__ hout,       // (B,U) bf16 out
    int t, int mt, int nt,
    ushort_t* tA, ushort_t* tB)
{
  constexpr int NPHASE = (LAYER == 0) ? 1 : 2;
  constexpr bool IS_L0 = (LAYER == 0);
  constexpr int K = NPHASE * 512;

  const int tid  = threadIdx.x;
  const int wv   = tid >> 6;
  const int lane = tid & 63;
  const int qd   = lane >> 4;     // quad 0..3
  const int l16  = lane & 15;
  const int wave_m = wv >> 1;     // 0..1
  const int wave_n = wv & 1;      // 0..1
  const int m0 = mt * 128, n0 = nt * 128;

  // Per-lane staging identity: chunk i = cc2*256 + wv*64 + lane over the
  // 1024 16B-chunks of a 128x64 tile; r = i>>3 (row), j = i&7 (LDS slot).
  // Source chunk for slot j is (j + r) & 7.
  int srow[4], scol[4];
  #pragma unroll
  for (int cc2 = 0; cc2 < 4; ++cc2){
    int i = cc2 * 256 + wv * 64 + lane;
    srow[cc2] = i >> 3;
    scol[cc2] = ((i & 7) + (i >> 3)) & 7;
  }

  // Per-lane LDS read offsets (elements) for frag (ks, w): row R, chunk q =
  // ks*4+qd lives at slot (q - R) & 7. Independent of k0/ph -> precompute.
  int aoff[2][4], boff[2][4];
  #pragma unroll
  for (int ks = 0; ks < 2; ++ks){
    #pragma unroll
    for (int w = 0; w < 4; ++w){
      int Ra = wave_m * 64 + w * 16 + l16;
      int Rb = wave_n * 64 + w * 16 + l16;
      int q  = ks * 4 + qd;
      aoff[ks][w] = Ra * 64 + ((q - Ra) & 7) * 8;
      boff[ks][w] = Rb * 64 + ((q - Rb) & 7) * 8;
    }
  }

  floatx4 acc[4][4];
  #pragma unroll
  for (int i = 0; i < 4; ++i)
    #pragma unroll
    for (int j = 0; j < 4; ++j) acc[i][j] = (floatx4){0.f, 0.f, 0.f, 0.f};

  #pragma unroll
  for (int ph = 0; ph < NPHASE; ++ph){
    const ushort_t* A = (NPHASE == 2 && ph == 1) ? A1 : A0;
    for (int k0 = 0; k0 < 512; k0 += 64){
      #pragma unroll
      for (int cc2 = 0; cc2 < 4; ++cc2){
        int ibase = cc2 * 256 + wv * 64;
        const ushort_t* ga = A + (size_t)(m0 + srow[cc2]) * U_ + k0 + scol[cc2] * 8;
        __builtin_amdgcn_global_load_lds(AS1(ga), AS3(&tA[ibase * 8]), 16, 0, 0);
        const ushort_t* gb = Bt + (size_t)(n0 + srow[cc2]) * K + ph * 512 + k0 + scol[cc2] * 8;
        __builtin_amdgcn_global_load_lds(AS1(gb), AS3(&tB[ibase * 8]), 16, 0, 0);
      }
      __syncthreads();

      #pragma unroll
      for (int ks = 0; ks < 2; ++ks){
        short8 af[4], bfr[4];
        #pragma unroll
        for (int wm = 0; wm < 4; ++wm)
          af[wm] = *(const short8*)&tA[aoff[ks][wm]];
        #pragma unroll
        for (int wn = 0; wn < 4; ++wn)
          bfr[wn] = *(const short8*)&tB[boff[ks][wn]];
        #pragma unroll
        for (int wm = 0; wm < 4; ++wm)
          #pragma unroll
          for (int wn = 0; wn < 4; ++wn)
            acc[wm][wn] = __builtin_amdgcn_mfma_f32_16x16x32_bf16(af[wm], bfr[wn], acc[wm][wn], 0, 0, 0);
      }
      __syncthreads();
    }
  }

  // ---- epilogue: LSTM cell, fully in-register per lane ----
  const int u  = nt * 32 + wave_n * 16 + l16;
  const int pb = nt * 128 + wave_n * 64 + l16;
  const float bi = biasp[pb], bf_ = biasp[pb + 16], bg = biasp[pb + 32], bo = biasp[pb + 48];
  float wi = 0.f, wf = 0.f, wg = 0.f, wo = 0.f;
  if (IS_L0){ wi = W0p[pb]; wf = W0p[pb + 16]; wg = W0p[pb + 32]; wo = W0p[pb + 48]; }

  #pragma unroll
  for (int wm = 0; wm < 4; ++wm){
    #pragma unroll
    for (int reg = 0; reg < 4; ++reg){
      int b = m0 + wave_m * 64 + wm * 16 + qd * 4 + reg;
      float zi = acc[wm][0][reg] + bi;
      float zf = acc[wm][1][reg] + bf_;
      float zg = acc[wm][2][reg] + bg;
      float zo = acc[wm][3][reg] + bo;
      if (IS_L0){
        float xv = x[(size_t)b * T_ + t];
        zi += xv * wi; zf += xv * wf; zg += xv * wg; zo += xv * wo;
      }
      int mk = mask[(size_t)b * T_ + t];
      size_t su = (size_t)b * U_ + u;
      float c_old = cbuf[su];
      float i_ = sigm(zi), f_ = sigm(zf), g_ = tanh_fast(zg), o_ = sigm(zo);
      float c_new = f_ * c_old + i_ * g_;
      float h_new = o_ * tanh_fast(c_new);
      ushort_t hb = mk ? f2bf(h_new) : hprev[su];
      cbuf[su] = mk ? c_new : c_old;
      hout[su] = hb;
    }
  }
}

// ---------------------------------------------------------------------------
// One wavefront phase: L0(t=s), L1(t=s-1), L2(t=s-2) are independent ->
// 768 blocks (3 tasks x 256 tiles) = 3 blocks/CU. task = lin>>8 so blocks
// {lin, lin+256, lin+512} (same tile, tasks 0/1/2) land on the same CU under
// round-robin XCD dispatch -> per-CU load is uniform (16+32+32 K-iters) and
// the three tasks share mask/x cachelines in L1.
// ---------------------------------------------------------------------------
__global__ __launch_bounds__(256, 3) void lstm_phase(
    const ushort_t* __restrict__ Bt0, const ushort_t* __restrict__ Bt1,
    const ushort_t* __restrict__ Bt2, const float* __restrict__ biasp,
    const float* __restrict__ W0p, const float* __restrict__ x,
    const int* __restrict__ mask,
    ushort_t* h00, ushort_t* h01, ushort_t* h10, ushort_t* h11,
    ushort_t* h20, ushort_t* h21,
    float* c0, float* c1, float* c2,
    int s)
{
  __shared__ __align__(16) ushort_t tA[128 * 64];
  __shared__ __align__(16) ushort_t tB[128 * 64];

  const int lin  = blockIdx.x;
  const int task = lin >> 8;        // 0..2
  const int tile = lin & 255;       // 0..255
  const int mt = tile >> 4, nt = tile & 15;

  ushort_t* h0[2] = {h00, h01};
  ushort_t* h1[2] = {h10, h11};
  ushort_t* h2[2] = {h20, h21};

  if (task == 0){
    if (s >= 100) return;
    int t = s, p = t & 1;
    do_task<0>(h0[p], nullptr, Bt0, biasp, W0p, x, mask,
               c0, h0[p], h0[p ^ 1], t, mt, nt, tA, tB);
  } else if (task == 1){
    if (s < 1 || s > 100) return;
    int t = s - 1, p = t & 1;
    do_task<1>(h0[p ^ 1], h1[p], Bt1, biasp + NG_, nullptr, x, mask,
               c1, h1[p], h1[p ^ 1], t, mt, nt, tA, tB);
  } else {
    if (s < 2) return;
    int t = s - 2, p = t & 1;
    do_task<2>(h1[p ^ 1], h2[p], Bt2, biasp + 2 * NG_, nullptr, x, mask,
               c2, h2[p], h2[p ^ 1], t, mt, nt, tA, tB);
  }
}

// ---------------------------------------------------------------------------
// Head: logits = h2 @ Wd + bd, softmax. One wave per batch row.
// ---------------------------------------------------------------------------
__global__ __launch_bounds__(256) void head_softmax(
    const ushort_t* __restrict__ h2, const float* __restrict__ Wd,
    const float* __restrict__ bd, float* __restrict__ out)
{
  int wv = threadIdx.x >> 6, lane = threadIdx.x & 63;
  int row = blockIdx.x * 4 + wv;
  const ushort_t* hr = h2 + (size_t)row * U_;

  float acc[C_];
  #pragma unroll
  for (int c = 0; c < C_; ++c) acc[c] = 0.f;

  short8 hv = *(const short8*)&hr[lane * 8];
  #pragma unroll
  for (int j = 0; j < 8; ++j){
    float hf = bf2f((ushort_t)hv[j]);
    int k = lane * 8 + j;
    #pragma unroll
    for (int c = 0; c < C_; ++c) acc[c] += hf * Wd[k * C_ + c];
  }
  #pragma unroll
  for (int c = 0; c < C_; ++c){
    float v = acc[c];
    #pragma unroll
    for (int off = 32; off > 0; off >>= 1) v += __shfl_xor(v, off);
    acc[c] = v + bd[c];
  }
  float mx = acc[0];
  #pragma unroll
  for (int c = 1; c < C_; ++c) mx = fmaxf(mx, acc[c]);
  float e[C_]; float s = 0.f;
  #pragma unroll
  for (int c = 0; c < C_; ++c){ e[c] = __expf(acc[c] - mx); s += e[c]; }
  float inv = 1.0f / s;
  if (lane == 0){
    #pragma unroll
    for (int c = 0; c < C_; ++c) out[(size_t)row * C_ + c] = e[c] * inv;
  }
}

// ---------------------------------------------------------------------------
extern "C" void kernel_launch(void* const* d_in, const int* in_sizes, int n_in,
                              void* d_out, int out_size, void* d_ws, size_t ws_size,
                              hipStream_t stream)
{
  const float* x  = (const float*)d_in[0];
  const int*  mask= (const int*)  d_in[1];
  const float* W0 = (const float*)d_in[2];
  const float* U0 = (const float*)d_in[3];
  const float* b0 = (const float*)d_in[4];
  const float* W1 = (const float*)d_in[5];
  const float* U1 = (const float*)d_in[6];
  const float* b1 = (const float*)d_in[7];
  const float* W2 = (const float*)d_in[8];
  const float* U2 = (const float*)d_in[9];
  const float* b2 = (const float*)d_in[10];
  const float* Wd = (const float*)d_in[11];
  const float* bd = (const float*)d_in[12];
  float* out = (float*)d_out;

  char* ws = (char*)d_ws;
  size_t off = 0;
  auto alloc = [&](size_t sz) -> char* {
    char* p = ws + off; off = (off + sz + 255) & ~(size_t)255; return p;
  };
  ushort_t* Bt0  = (ushort_t*)alloc((size_t)NG_ * 512 * 2);
  ushort_t* Bt1  = (ushort_t*)alloc((size_t)NG_ * 1024 * 2);
  ushort_t* Bt2  = (ushort_t*)alloc((size_t)NG_ * 1024 * 2);
  float*    W0p  = (float*)alloc((size_t)NG_ * 4);
  float*    biasp= (float*)alloc((size_t)3 * NG_ * 4);

  // State: h[3][2] (bf16) + c[3] (fp32), one contiguous memset region.
  const size_t hsz = (size_t)B_ * U_ * 2;
  const size_t csz = (size_t)B_ * U_ * 4;
  char* state = alloc(6 * hsz + 3 * csz);
  ushort_t* hb[3][2]; float* cb[3];
  {
    char* pp = state;
    for (int l = 0; l < 3; ++l)
      for (int par = 0; par < 2; ++par){ hb[l][par] = (ushort_t*)pp; pp += hsz; }
    for (int l = 0; l < 3; ++l){ cb[l] = (float*)pp; pp += csz; }
  }

  hipMemsetAsync(state, 0, 6 * hsz + 3 * csz, stream);

  const int total = NG_ * 512 + 2 * NG_ * 1024 + NG_ + 3 * NG_;
  convert_weights<<<(total + 255) / 256, 256, 0, stream>>>(
      W0, U0, b0, W1, U1, b1, W2, U2, b2, Bt0, Bt1, Bt2, W0p, biasp);

  for (int s = 0; s < 102; ++s){
    lstm_phase<<<768, 256, 0, stream>>>(
        Bt0, Bt1, Bt2, biasp, W0p, x, mask,
        hb[0][0], hb[0][1], hb[1][0], hb[1][1], hb[2][0], hb[2][1],
        cb[0], cb[1], cb[2], s);
  }

  // T=100: layer-2 final h (t=99) lands in parity-0 buffer.
  head_softmax<<<B_ / 4, 256, 0, stream>>>(hb[2][0], Wd, bd, out);
}